// Round 6
// baseline (3666.743 us; speedup 1.0000x reference)
//
#include <hip/hip_runtime.h>
#include <hip/hip_bf16.h>

#define T_STEPS 256
#define BATCH 64
#define HID 512
#define GATES 3072
#define NLAYERS 4
#define BT_GROUPS 4
#define GBLK 16            // col-blocks per bt-group; each owns 32 h-cols
#define SCAN_THREADS 256
#define HSTR 520           // h-tile LDS k-stride (elems); 1040 B, 16B-aligned rows
#define GLP 164            // gl float stride (160 + pad 4)
#define POLL_VALVE 4096    // bounded spin: fails fast (NaN), never hangs

typedef __bf16 bf16_t;
typedef _Float16 fp16_t;
typedef __attribute__((ext_vector_type(8))) __bf16 bf16x8;
typedef __attribute__((ext_vector_type(4))) float f32x4;
typedef __attribute__((ext_vector_type(4))) unsigned int u32x4;

__device__ __forceinline__ float sigm(float x){ return 1.0f/(1.0f + __expf(-x)); }
__device__ __forceinline__ float tanh_f(float x){ return 2.0f/(1.0f + __expf(-2.0f*x)) - 1.0f; }
__device__ __forceinline__ unsigned short f2bf(float x){ __bf16 b=(__bf16)x; return __builtin_bit_cast(unsigned short, b); }

// ---- transpose fp32 [R][C] -> bf16 [C][R] ----
__global__ void transpose_cast_kernel(const float* __restrict__ src, unsigned short* __restrict__ dst, int R, int C){
  __shared__ float tile[32][33];
  int tx = threadIdx.x & 31, ty = threadIdx.x >> 5;
  int c0 = blockIdx.x*32, r0 = blockIdx.y*32;
  #pragma unroll
  for(int i=0;i<4;i++){ int r = r0 + ty + i*8; tile[ty+i*8][tx] = src[(size_t)r*C + c0 + tx]; }
  __syncthreads();
  #pragma unroll
  for(int i=0;i<4;i++){ int c = c0 + ty + i*8; dst[(size_t)c*R + r0 + tx] = f2bf(tile[tx][ty+i*8]); }
}

// ---- inputs (B,T,D) fp32 -> masked bf16 (T,B,D) ----
__global__ void prep_x0_kernel(const float* __restrict__ inp, const int* __restrict__ lens, unsigned short* __restrict__ x0){
  int idx = blockIdx.x*blockDim.x + threadIdx.x;
  int e = idx*4;
  int d = e & (HID-1);
  int tb = e >> 9;
  int b = tb & (BATCH-1);
  int t = tb >> 6;
  const float4 v = *(const float4*)(inp + ((size_t)b*T_STEPS + t)*HID + d);
  float m = (t < lens[b]) ? 1.f : 0.f;
  ushort4 u; u.x=f2bf(v.x*m); u.y=f2bf(v.y*m); u.z=f2bf(v.z*m); u.w=f2bf(v.w*m);
  *(ushort4*)(x0 + ((size_t)t*BATCH + b)*HID + d) = u;
}

// ---- xi GEMM: C[m][n] = A[m][:] @ BT[n][:],  M=16384, N=3072, K=512, out fp16 ----
__global__ void __launch_bounds__(256,2)
xi_gemm_kernel(const unsigned short* __restrict__ A,   // [16384][512] bf16
               const unsigned short* __restrict__ BT,  // [3072][512] bf16 (WihT)
               fp16_t* __restrict__ C)                  // [16384][3072] fp16
{
  __shared__ __align__(16) unsigned short As[128*72];
  __shared__ __align__(16) unsigned short Bs[128*72];
  const int tid = threadIdx.x, lane = tid & 63, wv = tid >> 6;
  const int frow = lane & 15, quad = lane >> 4;
  const int m0 = blockIdx.x*128, n0 = blockIdx.y*128;
  const int mh = (wv>>1)*64, nh = (wv&1)*64;
  const int sr = tid>>1, sk = (tid&1)*32;
  f32x4 acc[4][4];
  #pragma unroll
  for(int mt=0;mt<4;mt++)
    #pragma unroll
    for(int nt=0;nt<4;nt++) acc[mt][nt] = (f32x4){0.f,0.f,0.f,0.f};

  for(int kc=0;kc<512;kc+=64){
    #pragma unroll
    for(int i=0;i<4;i++){
      *(uint4*)(As + sr*72 + sk + i*8) = *(const uint4*)(A + (size_t)(m0+sr)*512 + kc + sk + i*8);
      *(uint4*)(Bs + sr*72 + sk + i*8) = *(const uint4*)(BT + (size_t)(n0+sr)*512 + kc + sk + i*8);
    }
    __syncthreads();
    #pragma unroll
    for(int ks=0;ks<2;ks++){
      bf16x8 av[4], bv[4];
      #pragma unroll
      for(int mt=0;mt<4;mt++) av[mt] = *(const bf16x8*)(As + (mh+mt*16+frow)*72 + ks*32 + quad*8);
      #pragma unroll
      for(int nt=0;nt<4;nt++) bv[nt] = *(const bf16x8*)(Bs + (nh+nt*16+frow)*72 + ks*32 + quad*8);
      #pragma unroll
      for(int mt=0;mt<4;mt++)
        #pragma unroll
        for(int nt=0;nt<4;nt++)
          acc[mt][nt] = __builtin_amdgcn_mfma_f32_16x16x32_bf16(av[mt], bv[nt], acc[mt][nt],0,0,0);
    }
    __syncthreads();
  }
  #pragma unroll
  for(int mt=0;mt<4;mt++)
    #pragma unroll
    for(int nt=0;nt<4;nt++)
      #pragma unroll
      for(int r4=0;r4<4;r4++)
        C[(size_t)(m0+mh+mt*16+quad*4+r4)*GATES + n0+nh+nt*16+frow] = (fp16_t)acc[mt][nt][r4];
}

// ---- fused per-layer scan (h-recurrence only; xi precomputed) ----
// Proven round-4 skeleton: SELF-FLAGGING exchange (Hseq 0xFF sentinel, dword
// atomicity), block-coalesced poll + rule-18 "+v" fence, Al LDS staging (b2),
// K-split MFMA + gl reduce (b3), combine, register-direct publish.
//
// ROUND-6 CHANGE: 32 h-cols per block (64 blocks total). Halves the number of
// polling blocks (fabric contention) and producers per bt-group (32 -> 16,
// smaller straggler max). Per-block: Bf[2][5][4] register-resident Whh
// (~160 VGPR), 40 MFMAs/wave/step, combine handles 2 cols/thread.
//
// ZERO-GROWTH ALIASING: non-rev layers publish INTO the output buffer
// (Hseq==xdst layout, tcur==s); rev layers use a dead buffer.
__global__ void __launch_bounds__(SCAN_THREADS,1)
scan_kernel(const fp16_t* __restrict__ Xi,             // [T*B][3072] fp16
            const unsigned short* __restrict__ WhhT,   // [2560][512] bf16
            const float* __restrict__ bias_l,
            const int* __restrict__ lens,
            unsigned short* __restrict__ Hseq,         // [T][64][512] bf16, 0xFF-sentinel
            unsigned short* __restrict__ xdst,         // bf16 (T,B,H); rev layers only
            float* __restrict__ dout,                  // fp32 (B,T,H); last layer only
            int rev)
{
  __shared__ __align__(16) unsigned short Al[16*HSTR];
  __shared__ float gl[64*GLP];
  __shared__ float bl[160];
  __shared__ int ll[16];

  const int tid = threadIdx.x;
  const int bt  = blockIdx.x & (BT_GROUPS-1);
  const int G   = blockIdx.x >> 2;                     // 0..15, owns cols G*32..+32
  const int lane = tid & 63, wv = tid >> 6;
  const int frow = lane & 15, quad = lane >> 4;

  for(int i=tid;i<160;i+=SCAN_THREADS) bl[i] = bias_l[(i>>5)*HID + G*32 + (i&31)];
  if(tid<16) ll[tid] = lens[bt*16+tid];
  __syncthreads();

  // register-resident W_hh fragments: 2 col-tiles x 5 gates x 4 ksteps
  bf16x8 Bf[2][5][4];
  #pragma unroll
  for(int c=0;c<2;c++)
    #pragma unroll
    for(int q=0;q<5;q++)
      #pragma unroll
      for(int j=0;j<4;j++)
        Bf[c][q][j] = *(const bf16x8*)(WhhT + (size_t)(q*HID + G*32 + c*16 + frow)*HID + (wv + j*4)*32 + quad*8);

  // combine constants: each thread owns (row cr, cols jj and jj+16)
  const int cr = tid >> 4;           // 0..15
  const int jj = tid & 15;           // 0..15
  const int brow_g = bt*16 + cr;
  const int hc0    = G*32 + jj;      // col-tile 0
  const int hc1    = G*32 + 16 + jj; // col-tile 1
  const int L_r = ll[cr];
  float cst[2] = {0.f,0.f}, hs[2] = {0.f,0.f};
  unsigned short hbf[2] = {0,0}; int tprev=0;

  // poll addresses are loop-invariant except for the slot offset
  const size_t pofs[4] = {
    (size_t)((tid      )>>6)*HID + (size_t)((tid      )&63)*8,
    (size_t)((tid+256  )>>6)*HID + (size_t)((tid+256  )&63)*8,
    (size_t)((tid+512  )>>6)*HID + (size_t)((tid+512  )&63)*8,
    (size_t)((tid+768  )>>6)*HID + (size_t)((tid+768  )&63)*8 };

  for(int s=0; s<T_STEPS; s++){
    // ---- phase 1 (rev only): outputs for previous step (fire-and-forget) ----
    if(rev && s>0){
      if(dout){
        dout[((size_t)brow_g*T_STEPS + tprev)*HID + hc0] = hs[0];
        dout[((size_t)brow_g*T_STEPS + tprev)*HID + hc1] = hs[1];
      } else {
        xdst[((size_t)tprev*BATCH + brow_g)*HID + hc0] = hbf[0];
        xdst[((size_t)tprev*BATCH + brow_g)*HID + hc1] = hbf[1];
      }
    }

    // ---- phase 2: xi prefetch (overlaps poll latency) + poll h(s-1) ----
    bool valid = s < L_r;
    int tcur = rev ? (valid ? (L_r-1-s) : s) : s;
    const fp16_t* xr = Xi + ((size_t)tcur*BATCH + brow_g)*GATES + G*32 + jj;
    fp16_t xv[2][6];
    #pragma unroll
    for(int c=0;c<2;c++)
      #pragma unroll
      for(int q=0;q<6;q++)
        xv[c][q] = xr[c*16 + q*512];

    u32x4 hv[4];
    if(s==0){
      #pragma unroll
      for(int i=0;i<4;i++) hv[i] = (u32x4){0u,0u,0u,0u};
    } else {
      const unsigned short* hb = Hseq + (size_t)(s-1)*BATCH*HID + (size_t)bt*16*HID;
      int it = 0;
      while(1){
        #pragma unroll
        for(int i=0;i<4;i++){
          const unsigned short* p = hb + pofs[i];
          asm volatile("global_load_dwordx4 %0, %1, off sc0 sc1" : "=v"(hv[i]) : "v"(p) : "memory");
        }
        // RULE-18 FENCE: tie hv to the waitcnt so the sentinel compares
        // below CANNOT be scheduled before the loads complete.
        asm volatile("s_waitcnt vmcnt(0)"
                     : "+v"(hv[0]), "+v"(hv[1]), "+v"(hv[2]), "+v"(hv[3])
                     :: "memory");
        __builtin_amdgcn_sched_barrier(0);
        unsigned int bad = 0u;
        #pragma unroll
        for(int i=0;i<4;i++){
          bad |= (unsigned)(hv[i][0] == 0xFFFFFFFFu);
          bad |= (unsigned)(hv[i][1] == 0xFFFFFFFFu);
          bad |= (unsigned)(hv[i][2] == 0xFFFFFFFFu);
          bad |= (unsigned)(hv[i][3] == 0xFFFFFFFFu);
        }
        if(!bad) break;
        if(++it > POLL_VALVE) break;        // fail fast (NaN), never hang
        __builtin_amdgcn_s_sleep(1);        // ~64 cy backoff
      }
    }
    #pragma unroll
    for(int i=0;i<4;i++){
      int idx = tid + i*256;
      *(u32x4*)(Al + (idx>>6)*HSTR + (idx&63)*8) = hv[i];
    }
    __syncthreads();  // b2: h staged

    // ---- phase 3: MFMAs (K split mod 4 across waves) + gate partials to LDS ----
    f32x4 acc[2][5];
    #pragma unroll
    for(int c=0;c<2;c++)
      #pragma unroll
      for(int q=0;q<5;q++) acc[c][q] = (f32x4){0.f,0.f,0.f,0.f};
    #pragma unroll
    for(int j=0;j<4;j++){
      bf16x8 a = *(const bf16x8*)((const bf16_t*)Al + (size_t)frow*HSTR + (wv + j*4)*32 + quad*8);
      #pragma unroll
      for(int c=0;c<2;c++)
        #pragma unroll
        for(int q=0;q<5;q++)
          acc[c][q] = __builtin_amdgcn_mfma_f32_16x16x32_bf16(a, Bf[c][q][j], acc[c][q],0,0,0);
    }
    #pragma unroll
    for(int c=0;c<2;c++)
      #pragma unroll
      for(int q=0;q<5;q++)
        #pragma unroll
        for(int r4=0;r4<4;r4++)
          gl[(wv*16 + quad*4 + r4)*GLP + (c*5+q)*16 + frow] = acc[c][q][r4];   // C: col=lane&15, row=quad*4+reg
    __syncthreads();  // b3

    // ---- phase 4: combine (2 cols/thread) + direct publish of h(s) ----
    {
      float m = valid ? 1.f : 0.f;
      tprev = tcur;
      #pragma unroll
      for(int c=0;c<2;c++){
        float ga[5];
        #pragma unroll
        for(int q=0;q<5;q++){
          float sum = bl[q*32 + c*16 + jj];
          #pragma unroll
          for(int w=0;w<4;w++) sum += gl[(w*16+cr)*GLP + (c*5+q)*16 + jj];
          ga[q] = sum + (float)xv[c][q];
        }
        float gi=sigm(ga[0]), gf=sigm(ga[1]), gcv=tanh_f(ga[2]), go=sigm(ga[3]), grv=sigm(ga[4]);
        cst[c] = (gf*cst[c] + gi*gcv) * m;
        hs[c]  = (grv*(go*tanh_f(cst[c])) + (1.f-grv)*(float)xv[c][5]) * m;
        hbf[c] = f2bf(hs[c]);

        // pair-pack neighboring cols so every store is a whole (atomic) dword
        int up = __shfl_down((int)(unsigned int)hbf[c], 1);
        if((jj&1)==0){
          unsigned int packed = (unsigned int)hbf[c] | (((unsigned int)up & 0xFFFFu) << 16);
          unsigned int* dst = (unsigned int*)(Hseq + (size_t)s*BATCH*HID + (size_t)brow_g*HID + G*32 + c*16 + jj);
          asm volatile("global_store_dword %0, %1, off sc0 sc1" :: "v"(dst), "v"(packed) : "memory");
        }
      }
    }
    // no trailing barrier: next-iter Al writes fenced from this iter's phase-3
    // reads by b3; next-iter gl writes fenced from phase-4 reads by next b2.
  }

  // epilogue (rev only): outputs for step T-1
  if(rev){
    if(dout){
      dout[((size_t)brow_g*T_STEPS + tprev)*HID + hc0] = hs[0];
      dout[((size_t)brow_g*T_STEPS + tprev)*HID + hc1] = hs[1];
    } else {
      xdst[((size_t)tprev*BATCH + brow_g)*HID + hc0] = hbf[0];
      xdst[((size_t)tprev*BATCH + brow_g)*HID + hc1] = hbf[1];
    }
  }
}

extern "C" void kernel_launch(void* const* d_in, const int* in_sizes, int n_in,
                              void* d_out, int out_size, void* d_ws, size_t ws_size,
                              hipStream_t stream){
  const float* inp    = (const float*)d_in[0];
  const float* weight = (const float*)d_in[1];
  const float* bias   = (const float*)d_in[2];
  const int*   lens   = (const int*)d_in[3];
  float* dout = (float*)d_out;

  char* ws = (char*)d_ws;
  size_t off = 0;
  const size_t WTL = (size_t)(3072+2560)*512;   // per-layer transposed bf16 elements
  unsigned short* WT = (unsigned short*)(ws+off); off += (size_t)NLAYERS*WTL*2;        // 23.1 MB
  unsigned short* x0 = (unsigned short*)(ws+off); off += (size_t)T_STEPS*BATCH*HID*2;  // 16.8 MB
  unsigned short* xA = (unsigned short*)(ws+off); off += (size_t)T_STEPS*BATCH*HID*2;  // 16.8 MB
  fp16_t* Xi = (fp16_t*)(ws+off); off += (size_t)T_STEPS*BATCH*GATES*2;                // 100.7 MB
  // total 157.3 MB -- no growth vs the proven layout (Hseq aliases x0/xA)

  const size_t HSEQ_BYTES = (size_t)T_STEPS*BATCH*HID*2;                               // 16.8 MB

  const size_t WS_L = (size_t)512*3072 + (size_t)512*2560; // per-layer fp32 weight elements
  for(int l=0;l<NLAYERS;l++){
    const float* wih = weight + l*WS_L;
    const float* whh = wih + (size_t)512*3072;
    unsigned short* wihT = WT + l*WTL;
    unsigned short* whhT = wihT + (size_t)3072*512;
    transpose_cast_kernel<<<dim3(3072/32,512/32),256,0,stream>>>(wih, wihT, 512, 3072);
    transpose_cast_kernel<<<dim3(2560/32,512/32),256,0,stream>>>(whh, whhT, 512, 2560);
  }
  prep_x0_kernel<<<8192,256,0,stream>>>(inp, lens, x0);

  // layer plan (Hseq aliases only dead or output buffers):
  //  l=0: gemm reads x0 -> Hseq = output = xA          (non-rev: publish IS output)
  //  l=1: gemm reads xA -> Hseq = xA (dead), out = x0  (rev)
  //  l=2: gemm reads x0 -> Hseq = output = xA          (non-rev)
  //  l=3: gemm reads xA -> Hseq = x0 (dead), out = dout (rev)
  const unsigned short* gemm_in[4] = {x0, xA, x0, xA};
  unsigned short*       hseq_l[4]  = {xA, xA, xA, x0};
  unsigned short*       xdst_l[4]  = {nullptr, x0, nullptr, nullptr};

  for(int l=0;l<NLAYERS;l++){
    xi_gemm_kernel<<<dim3(128,24),256,0,stream>>>(gemm_in[l], WT + l*WTL, Xi);
    hipMemsetAsync(hseq_l[l], 0xFF, HSEQ_BYTES, stream);  // sentinel fill (after gemm consumed it)
    scan_kernel<<<BT_GROUPS*GBLK, SCAN_THREADS, 0, stream>>>(
        Xi, WT + l*WTL + (size_t)3072*512,
        bias + (size_t)l*2560, lens, hseq_l[l],
        xdst_l[l], (l==3) ? dout : nullptr, l&1);
  }
}

// Round 7
// 3394.975 us; speedup vs baseline: 1.0801x; 1.0801x over previous
//
#include <hip/hip_runtime.h>
#include <hip/hip_bf16.h>

#define T_STEPS 256
#define BATCH 64
#define HID 512
#define GATES 3072
#define NLAYERS 4
#define BT_GROUPS 4
#define GBLK 32            // blocks per bt-group (each owns 16 h-cols)
#define SCAN_THREADS 256
#define HSTR 520           // h-tile LDS k-stride (elems); 1040 B, 16B-aligned rows
#define GLP 84             // gl float stride (80 + pad)
#define POLL_VALVE 4096    // bounded spin: fails fast (NaN), never hangs

typedef __bf16 bf16_t;
typedef _Float16 fp16_t;
typedef __attribute__((ext_vector_type(8))) __bf16 bf16x8;
typedef __attribute__((ext_vector_type(4))) float f32x4;
typedef __attribute__((ext_vector_type(4))) unsigned int u32x4;

__device__ __forceinline__ float sigm(float x){ return 1.0f/(1.0f + __expf(-x)); }
__device__ __forceinline__ float tanh_f(float x){ return 2.0f/(1.0f + __expf(-2.0f*x)) - 1.0f; }
__device__ __forceinline__ unsigned short f2bf(float x){ __bf16 b=(__bf16)x; return __builtin_bit_cast(unsigned short, b); }

// ---- transpose fp32 [R][C] -> bf16 [C][R] ----
__global__ void transpose_cast_kernel(const float* __restrict__ src, unsigned short* __restrict__ dst, int R, int C){
  __shared__ float tile[32][33];
  int tx = threadIdx.x & 31, ty = threadIdx.x >> 5;
  int c0 = blockIdx.x*32, r0 = blockIdx.y*32;
  #pragma unroll
  for(int i=0;i<4;i++){ int r = r0 + ty + i*8; tile[ty+i*8][tx] = src[(size_t)r*C + c0 + tx]; }
  __syncthreads();
  #pragma unroll
  for(int i=0;i<4;i++){ int c = c0 + ty + i*8; dst[(size_t)c*R + r0 + tx] = f2bf(tile[tx][ty+i*8]); }
}

// ---- inputs (B,T,D) fp32 -> masked bf16 (T,B,D) ----
__global__ void prep_x0_kernel(const float* __restrict__ inp, const int* __restrict__ lens, unsigned short* __restrict__ x0){
  int idx = blockIdx.x*blockDim.x + threadIdx.x;
  int e = idx*4;
  int d = e & (HID-1);
  int tb = e >> 9;
  int b = tb & (BATCH-1);
  int t = tb >> 6;
  const float4 v = *(const float4*)(inp + ((size_t)b*T_STEPS + t)*HID + d);
  float m = (t < lens[b]) ? 1.f : 0.f;
  ushort4 u; u.x=f2bf(v.x*m); u.y=f2bf(v.y*m); u.z=f2bf(v.z*m); u.w=f2bf(v.w*m);
  *(ushort4*)(x0 + ((size_t)t*BATCH + b)*HID + d) = u;
}

// ---- xi GEMM: C[m][n] = A[m][:] @ BT[n][:],  M=16384, N=3072, K=512, out fp16 ----
__global__ void __launch_bounds__(256,2)
xi_gemm_kernel(const unsigned short* __restrict__ A,   // [16384][512] bf16
               const unsigned short* __restrict__ BT,  // [3072][512] bf16 (WihT)
               fp16_t* __restrict__ C)                  // [16384][3072] fp16
{
  __shared__ __align__(16) unsigned short As[128*72];
  __shared__ __align__(16) unsigned short Bs[128*72];
  const int tid = threadIdx.x, lane = tid & 63, wv = tid >> 6;
  const int frow = lane & 15, quad = lane >> 4;
  const int m0 = blockIdx.x*128, n0 = blockIdx.y*128;
  const int mh = (wv>>1)*64, nh = (wv&1)*64;
  const int sr = tid>>1, sk = (tid&1)*32;
  f32x4 acc[4][4];
  #pragma unroll
  for(int mt=0;mt<4;mt++)
    #pragma unroll
    for(int nt=0;nt<4;nt++) acc[mt][nt] = (f32x4){0.f,0.f,0.f,0.f};

  for(int kc=0;kc<512;kc+=64){
    #pragma unroll
    for(int i=0;i<4;i++){
      *(uint4*)(As + sr*72 + sk + i*8) = *(const uint4*)(A + (size_t)(m0+sr)*512 + kc + sk + i*8);
      *(uint4*)(Bs + sr*72 + sk + i*8) = *(const uint4*)(BT + (size_t)(n0+sr)*512 + kc + sk + i*8);
    }
    __syncthreads();
    #pragma unroll
    for(int ks=0;ks<2;ks++){
      bf16x8 av[4], bv[4];
      #pragma unroll
      for(int mt=0;mt<4;mt++) av[mt] = *(const bf16x8*)(As + (mh+mt*16+frow)*72 + ks*32 + quad*8);
      #pragma unroll
      for(int nt=0;nt<4;nt++) bv[nt] = *(const bf16x8*)(Bs + (nh+nt*16+frow)*72 + ks*32 + quad*8);
      #pragma unroll
      for(int mt=0;mt<4;mt++)
        #pragma unroll
        for(int nt=0;nt<4;nt++)
          acc[mt][nt] = __builtin_amdgcn_mfma_f32_16x16x32_bf16(av[mt], bv[nt], acc[mt][nt],0,0,0);
    }
    __syncthreads();
  }
  #pragma unroll
  for(int mt=0;mt<4;mt++)
    #pragma unroll
    for(int nt=0;nt<4;nt++)
      #pragma unroll
      for(int r4=0;r4<4;r4++)
        C[(size_t)(m0+mh+mt*16+quad*4+r4)*GATES + n0+nh+nt*16+frow] = (fp16_t)acc[mt][nt][r4];
}

// ---- fused per-layer scan (h-recurrence only; xi precomputed) ----
// Proven round-4 skeleton: SELF-FLAGGING exchange (Hseq 0xFF sentinel, dword
// atomicity), block-coalesced poll + rule-18 "+v" fence, Al LDS staging (b2),
// K-split MFMA + gl reduce (b3), combine, register-direct publish.
//
// ROUND-7 CHANGES (scheduling only, protocol identical):
//  1. xi prefetched ONE STEP AHEAD, issued right after the poll succeeds --
//     the poll's vmcnt(0) no longer drains fresh HBM loads (Xi streams from
//     HBM at ~900cy; previously serialized into every step's first poll round).
//  2. rev-layer output stores moved from pre-poll to post-poll: their ~600cy
//     retire hides under MFMA/combine instead of the poll drain.
//
// ZERO-GROWTH ALIASING: non-rev layers publish INTO the output buffer
// (Hseq==xdst layout, tcur==s); rev layers use a dead buffer.
__global__ void __launch_bounds__(SCAN_THREADS,1)
scan_kernel(const fp16_t* __restrict__ Xi,             // [T*B][3072] fp16
            const unsigned short* __restrict__ WhhT,   // [2560][512] bf16
            const float* __restrict__ bias_l,
            const int* __restrict__ lens,
            unsigned short* __restrict__ Hseq,         // [T][64][512] bf16, 0xFF-sentinel
            unsigned short* __restrict__ xdst,         // bf16 (T,B,H); rev layers only
            float* __restrict__ dout,                  // fp32 (B,T,H); last layer only
            int rev)
{
  __shared__ __align__(16) unsigned short Al[16*HSTR];
  __shared__ float gl[64*GLP];
  __shared__ float bl[80];
  __shared__ int ll[16];

  const int tid = threadIdx.x;
  const int bt  = blockIdx.x & (BT_GROUPS-1);
  const int g   = blockIdx.x >> 2;                     // 0..31
  const int lane = tid & 63, wv = tid >> 6;
  const int frow = lane & 15, quad = lane >> 4;

  for(int i=tid;i<80;i+=SCAN_THREADS) bl[i] = bias_l[(i>>4)*HID + g*16 + (i&15)];
  if(tid<16) ll[tid] = lens[bt*16+tid];
  __syncthreads();

  // register-resident W_hh fragments: 5 gate tiles x 4 ksteps (kstep = wv + 4j)
  bf16x8 Bf[5][4];
  #pragma unroll
  for(int q=0;q<5;q++)
    #pragma unroll
    for(int j=0;j<4;j++)
      Bf[q][j] = *(const bf16x8*)(WhhT + (size_t)(q*HID + g*16 + frow)*HID + (wv + j*4)*32 + quad*8);

  // combine constants: each thread owns one (row, col)
  const int cr = tid >> 4;           // 0..15
  const int jj = tid & 15;           // 0..15
  const int brow_g = bt*16 + cr;
  const int hcol   = g*16 + jj;
  const int L_r = ll[cr];
  float cst=0.f, hs=0.f;
  unsigned short hbf=0; int tprev=0;

  // poll addresses are loop-invariant except for the slot offset
  const size_t pofs[4] = {
    (size_t)((tid      )>>6)*HID + (size_t)((tid      )&63)*8,
    (size_t)((tid+256  )>>6)*HID + (size_t)((tid+256  )&63)*8,
    (size_t)((tid+512  )>>6)*HID + (size_t)((tid+512  )&63)*8,
    (size_t)((tid+768  )>>6)*HID + (size_t)((tid+768  )&63)*8 };

  // prologue: xi for step 0 (no poll at s=0, so no drain hazard)
  fp16_t xv[6];
  {
    int t0 = rev ? ((0 < L_r) ? (L_r-1) : 0) : 0;
    const fp16_t* xr = Xi + ((size_t)t0*BATCH + brow_g)*GATES + hcol;
    #pragma unroll
    for(int q=0;q<6;q++) xv[q] = xr[q*512];
  }

  for(int s=0; s<T_STEPS; s++){
    bool valid = s < L_r;
    int tcur = rev ? (valid ? (L_r-1-s) : s) : s;

    // ---- phase 2a: poll h(s-1) (block-coalesced, sentinel = the data) ----
    u32x4 hv[4];
    if(s==0){
      #pragma unroll
      for(int i=0;i<4;i++) hv[i] = (u32x4){0u,0u,0u,0u};
    } else {
      const unsigned short* hb = Hseq + (size_t)(s-1)*BATCH*HID + (size_t)bt*16*HID;
      int it = 0;
      while(1){
        #pragma unroll
        for(int i=0;i<4;i++){
          const unsigned short* p = hb + pofs[i];
          asm volatile("global_load_dwordx4 %0, %1, off sc0 sc1" : "=v"(hv[i]) : "v"(p) : "memory");
        }
        // RULE-18 FENCE: tie hv to the waitcnt so the sentinel compares
        // below CANNOT be scheduled before the loads complete.
        asm volatile("s_waitcnt vmcnt(0)"
                     : "+v"(hv[0]), "+v"(hv[1]), "+v"(hv[2]), "+v"(hv[3])
                     :: "memory");
        __builtin_amdgcn_sched_barrier(0);
        unsigned int bad = 0u;
        #pragma unroll
        for(int i=0;i<4;i++){
          bad |= (unsigned)(hv[i][0] == 0xFFFFFFFFu);
          bad |= (unsigned)(hv[i][1] == 0xFFFFFFFFu);
          bad |= (unsigned)(hv[i][2] == 0xFFFFFFFFu);
          bad |= (unsigned)(hv[i][3] == 0xFFFFFFFFu);
        }
        if(!bad) break;
        if(++it > POLL_VALVE) break;        // fail fast (NaN), never hang
        __builtin_amdgcn_s_sleep(1);        // ~64 cy backoff
      }
    }

    // ---- phase 2b: prefetch xi for step s+1 (retires under compute) ----
    fp16_t xn[6];
    if(s+1 < T_STEPS){
      int tnext = rev ? (((s+1) < L_r) ? (L_r-2-s) : (s+1)) : (s+1);
      const fp16_t* xr = Xi + ((size_t)tnext*BATCH + brow_g)*GATES + hcol;
      #pragma unroll
      for(int q=0;q<6;q++) xn[q] = xr[q*512];
    } else {
      #pragma unroll
      for(int q=0;q<6;q++) xn[q] = (fp16_t)0.f;
    }

    // ---- phase 2c (rev only): outputs for previous step (retire under compute) ----
    if(rev && s>0){
      if(dout) dout[((size_t)brow_g*T_STEPS + tprev)*HID + hcol] = hs;
      else     xdst[((size_t)tprev*BATCH + brow_g)*HID + hcol] = hbf;
    }

    // ---- phase 2d: stage h to LDS ----
    #pragma unroll
    for(int i=0;i<4;i++){
      int idx = tid + i*256;
      *(u32x4*)(Al + (idx>>6)*HSTR + (idx&63)*8) = hv[i];
    }
    __syncthreads();  // b2: h staged

    // ---- phase 3: MFMAs (K split mod 4 across waves) + gate partials to LDS ----
    f32x4 acc[5];
    #pragma unroll
    for(int q=0;q<5;q++) acc[q] = (f32x4){0.f,0.f,0.f,0.f};
    #pragma unroll
    for(int j=0;j<4;j++){
      bf16x8 a = *(const bf16x8*)((const bf16_t*)Al + (size_t)frow*HSTR + (wv + j*4)*32 + quad*8);
      #pragma unroll
      for(int q=0;q<5;q++)
        acc[q] = __builtin_amdgcn_mfma_f32_16x16x32_bf16(a, Bf[q][j], acc[q],0,0,0);
    }
    #pragma unroll
    for(int q=0;q<5;q++)
      #pragma unroll
      for(int r4=0;r4<4;r4++)
        gl[(wv*16 + quad*4 + r4)*GLP + q*16 + frow] = acc[q][r4];   // C: col=lane&15, row=quad*4+reg
    __syncthreads();  // b3

    // ---- phase 4: combine + direct publish of h(s) from registers ----
    {
      float ga[5];
      #pragma unroll
      for(int q=0;q<5;q++){
        float sum = bl[q*16+jj];
        #pragma unroll
        for(int w=0;w<4;w++) sum += gl[(w*16+cr)*GLP + q*16 + jj];
        ga[q] = sum + (float)xv[q];
      }
      float m = valid ? 1.f : 0.f;
      float gi=sigm(ga[0]), gf=sigm(ga[1]), gcv=tanh_f(ga[2]), go=sigm(ga[3]), grv=sigm(ga[4]);
      cst = (gf*cst + gi*gcv) * m;
      hs  = (grv*(go*tanh_f(cst)) + (1.f-grv)*(float)xv[5]) * m;
      hbf = f2bf(hs);
      tprev = tcur;

      // pair-pack neighboring cols so every store is a whole (atomic) dword
      int up = __shfl_down((int)(unsigned int)hbf, 1);
      if((jj&1)==0){
        unsigned int packed = (unsigned int)hbf | (((unsigned int)up & 0xFFFFu) << 16);
        unsigned int* dst = (unsigned int*)(Hseq + (size_t)s*BATCH*HID + (size_t)brow_g*HID + hcol);
        asm volatile("global_store_dword %0, %1, off sc0 sc1" :: "v"(dst), "v"(packed) : "memory");
      }
    }
    // carry the prefetched xi into the next step
    #pragma unroll
    for(int q=0;q<6;q++) xv[q] = xn[q];
    // no trailing barrier: next-iter Al writes fenced from this iter's phase-3
    // reads by b3; next-iter gl writes fenced from phase-4 reads by next b2.
  }

  // epilogue (rev only): outputs for step T-1
  if(rev){
    if(dout) dout[((size_t)brow_g*T_STEPS + tprev)*HID + hcol] = hs;
    else     xdst[((size_t)tprev*BATCH + brow_g)*HID + hcol] = hbf;
  }
}

extern "C" void kernel_launch(void* const* d_in, const int* in_sizes, int n_in,
                              void* d_out, int out_size, void* d_ws, size_t ws_size,
                              hipStream_t stream){
  const float* inp    = (const float*)d_in[0];
  const float* weight = (const float*)d_in[1];
  const float* bias   = (const float*)d_in[2];
  const int*   lens   = (const int*)d_in[3];
  float* dout = (float*)d_out;

  char* ws = (char*)d_ws;
  size_t off = 0;
  const size_t WTL = (size_t)(3072+2560)*512;   // per-layer transposed bf16 elements
  unsigned short* WT = (unsigned short*)(ws+off); off += (size_t)NLAYERS*WTL*2;        // 23.1 MB
  unsigned short* x0 = (unsigned short*)(ws+off); off += (size_t)T_STEPS*BATCH*HID*2;  // 16.8 MB
  unsigned short* xA = (unsigned short*)(ws+off); off += (size_t)T_STEPS*BATCH*HID*2;  // 16.8 MB
  fp16_t* Xi = (fp16_t*)(ws+off); off += (size_t)T_STEPS*BATCH*GATES*2;                // 100.7 MB
  // total 157.3 MB -- no growth vs the proven layout (Hseq aliases x0/xA)

  const size_t HSEQ_BYTES = (size_t)T_STEPS*BATCH*HID*2;                               // 16.8 MB

  const size_t WS_L = (size_t)512*3072 + (size_t)512*2560; // per-layer fp32 weight elements
  for(int l=0;l<NLAYERS;l++){
    const float* wih = weight + l*WS_L;
    const float* whh = wih + (size_t)512*3072;
    unsigned short* wihT = WT + l*WTL;
    unsigned short* whhT = wihT + (size_t)3072*512;
    transpose_cast_kernel<<<dim3(3072/32,512/32),256,0,stream>>>(wih, wihT, 512, 3072);
    transpose_cast_kernel<<<dim3(2560/32,512/32),256,0,stream>>>(whh, whhT, 512, 2560);
  }
  prep_x0_kernel<<<8192,256,0,stream>>>(inp, lens, x0);

  // layer plan (Hseq aliases only dead or output buffers):
  //  l=0: gemm reads x0 -> Hseq = output = xA          (non-rev: publish IS output)
  //  l=1: gemm reads xA -> Hseq = xA (dead), out = x0  (rev)
  //  l=2: gemm reads x0 -> Hseq = output = xA          (non-rev)
  //  l=3: gemm reads xA -> Hseq = x0 (dead), out = dout (rev)
  const unsigned short* gemm_in[4] = {x0, xA, x0, xA};
  unsigned short*       hseq_l[4]  = {xA, xA, xA, x0};
  unsigned short*       xdst_l[4]  = {nullptr, x0, nullptr, nullptr};

  for(int l=0;l<NLAYERS;l++){
    xi_gemm_kernel<<<dim3(128,24),256,0,stream>>>(gemm_in[l], WT + l*WTL, Xi);
    hipMemsetAsync(hseq_l[l], 0xFF, HSEQ_BYTES, stream);  // sentinel fill (after gemm consumed it)
    scan_kernel<<<BT_GROUPS*GBLK, SCAN_THREADS, 0, stream>>>(
        Xi, WT + l*WTL + (size_t)3072*512,
        bias + (size_t)l*2560, lens, hseq_l[l],
        xdst_l[l], (l==3) ? dout : nullptr, l&1);
  }
}

// Round 10
// 2909.674 us; speedup vs baseline: 1.2602x; 1.1668x over previous
//
#include <hip/hip_runtime.h>
#include <hip/hip_bf16.h>
#include <stdint.h>

#define T_STEPS 256
#define BATCH 64
#define HID 512
#define GATES 3072
#define NLAYERS 4
#define BT_GROUPS 4
#define GBLK 32            // blocks per bt-group (each owns 16 h-cols)
#define SCAN_THREADS 256
#define HSTR 520           // h-tile LDS k-stride (elems); 1040 B, 16B-aligned rows
#define GLP 84             // gl float stride (80 + pad)
#define POLL_VALVE 4096    // bounded spin: fails fast (NaN), never hangs

typedef __bf16 bf16_t;
typedef _Float16 fp16_t;
typedef __attribute__((ext_vector_type(8))) __bf16 bf16x8;
typedef __attribute__((ext_vector_type(4))) float f32x4;
typedef __attribute__((ext_vector_type(4))) unsigned int u32x4;

__device__ __forceinline__ float sigm(float x){ return 1.0f/(1.0f + __expf(-x)); }
__device__ __forceinline__ float tanh_f(float x){ return 2.0f/(1.0f + __expf(-2.0f*x)) - 1.0f; }
__device__ __forceinline__ unsigned short f2bf(float x){ __bf16 b=(__bf16)x; return __builtin_bit_cast(unsigned short, b); }

// async global->LDS, 16B per lane; LDS dest is wave-uniform base + lane*16.
// AS casts via uintptr_t (CK's amd_direct_load pattern): low 32 bits of a flat
// shared address are the LDS byte offset.
__device__ __forceinline__ void gl_lds16(const unsigned short* g, unsigned short* l){
  __builtin_amdgcn_global_load_lds(
      (const __attribute__((address_space(1))) void*)(uintptr_t)g,
      (__attribute__((address_space(3))) void*)(uintptr_t)l,
      16, 0, 0);
}

// ---- transpose fp32 [R][C] -> bf16 [C][R] ----
__global__ void transpose_cast_kernel(const float* __restrict__ src, unsigned short* __restrict__ dst, int R, int C){
  __shared__ float tile[32][33];
  int tx = threadIdx.x & 31, ty = threadIdx.x >> 5;
  int c0 = blockIdx.x*32, r0 = blockIdx.y*32;
  #pragma unroll
  for(int i=0;i<4;i++){ int r = r0 + ty + i*8; tile[ty+i*8][tx] = src[(size_t)r*C + c0 + tx]; }
  __syncthreads();
  #pragma unroll
  for(int i=0;i<4;i++){ int c = c0 + ty + i*8; dst[(size_t)c*R + r0 + tx] = f2bf(tile[tx][ty+i*8]); }
}

// ---- inputs (B,T,D) fp32 -> masked bf16 (T,B,D) ----
__global__ void prep_x0_kernel(const float* __restrict__ inp, const int* __restrict__ lens, unsigned short* __restrict__ x0){
  int idx = blockIdx.x*blockDim.x + threadIdx.x;
  int e = idx*4;
  int d = e & (HID-1);
  int tb = e >> 9;
  int b = tb & (BATCH-1);
  int t = tb >> 6;
  const float4 v = *(const float4*)(inp + ((size_t)b*T_STEPS + t)*HID + d);
  float m = (t < lens[b]) ? 1.f : 0.f;
  ushort4 u; u.x=f2bf(v.x*m); u.y=f2bf(v.y*m); u.z=f2bf(v.z*m); u.w=f2bf(v.w*m);
  *(ushort4*)(x0 + ((size_t)t*BATCH + b)*HID + d) = u;
}

// ---- xi GEMM: C[m][n] = A[m][:] @ BT[n][:],  M=16384, N=3072, K=512, out fp16 ----
// ROUND-10: staging via global_load_lds width=16 (m97 recipe). LDS is linear
// [128][64] bf16 (global_load_lds needs contiguous wave-ordered dest; the
// 16-way ds_read conflict is the same one m97 carried to 874 TF). Removes the
// register round-trip + per-thread address VALU that capped this gemm ~550 TF.
__global__ void __launch_bounds__(256,2)
xi_gemm_kernel(const unsigned short* __restrict__ A,   // [16384][512] bf16
               const unsigned short* __restrict__ BT,  // [3072][512] bf16 (WihT)
               fp16_t* __restrict__ C)                  // [16384][3072] fp16
{
  __shared__ __align__(16) unsigned short As[128*64];
  __shared__ __align__(16) unsigned short Bs[128*64];
  const int tid = threadIdx.x, lane = tid & 63, wv = tid >> 6;
  const int frow = lane & 15, quad = lane >> 4;
  const int m0 = blockIdx.x*128, n0 = blockIdx.y*128;
  const int mh = (wv>>1)*64, nh = (wv&1)*64;
  f32x4 acc[4][4];
  #pragma unroll
  for(int mt=0;mt<4;mt++)
    #pragma unroll
    for(int nt=0;nt<4;nt++) acc[mt][nt] = (f32x4){0.f,0.f,0.f,0.f};

  // per-lane global bases: row (wv*8 + lane>>3), col chunk (lane&7)*8 elems
  const unsigned short* gA0 = A  + (size_t)(m0 + wv*8 + (lane>>3))*512 + (lane&7)*8;
  const unsigned short* gB0 = BT + (size_t)(n0 + wv*8 + (lane>>3))*512 + (lane&7)*8;
  unsigned short* lA0 = As + (wv*8)*64;   // wave-uniform LDS bases
  unsigned short* lB0 = Bs + (wv*8)*64;

  for(int kc=0;kc<512;kc+=64){
    // stage A-tile[128][64] + B-tile[128][64]: 4 row-groups of 32 per wave,
    // each issue = 64 lanes x 16B = 8 rows x 128B
    #pragma unroll
    for(int i=0;i<4;i++){
      gl_lds16(gA0 + kc + (size_t)i*32*512, lA0 + i*32*64);
      gl_lds16(gB0 + kc + (size_t)i*32*512, lB0 + i*32*64);
    }
    asm volatile("s_waitcnt vmcnt(0)" ::: "memory");
    __syncthreads();
    #pragma unroll
    for(int ks=0;ks<2;ks++){
      bf16x8 av[4], bv[4];
      #pragma unroll
      for(int mt=0;mt<4;mt++) av[mt] = *(const bf16x8*)(As + (mh+mt*16+frow)*64 + ks*32 + quad*8);
      #pragma unroll
      for(int nt=0;nt<4;nt++) bv[nt] = *(const bf16x8*)(Bs + (nh+nt*16+frow)*64 + ks*32 + quad*8);
      #pragma unroll
      for(int mt=0;mt<4;mt++)
        #pragma unroll
        for(int nt=0;nt<4;nt++)
          acc[mt][nt] = __builtin_amdgcn_mfma_f32_16x16x32_bf16(av[mt], bv[nt], acc[mt][nt],0,0,0);
    }
    __syncthreads();
  }
  #pragma unroll
  for(int mt=0;mt<4;mt++)
    #pragma unroll
    for(int nt=0;nt<4;nt++)
      #pragma unroll
      for(int r4=0;r4<4;r4++)
        C[(size_t)(m0+mh+mt*16+quad*4+r4)*GATES + n0+nh+nt*16+frow] = (fp16_t)acc[mt][nt][r4];
}

// ---- fused per-layer scan -- BYTE-IDENTICAL to the proven round-4 kernel ----
// (642 us/dispatch verified; r5-r9 exchange experiments all lost to it.)
// SELF-FLAGGING exchange: Hseq[s][64][512] bf16, 0xFF-prefilled (bf16 NaN
// pattern, unproducible by finite math; masked rows give exact 0.0). A dword
// == 0xFFFFFFFF means "not yet written"; dword stores are atomic.
// RULE-18 FENCE: waitcnt asm takes hv[0..3] as "+v" + sched_barrier(0).
// BOUNDED SPIN: valve 4096 + s_sleep backoff (fail fast, never hang).
// ZERO-GROWTH ALIASING: non-rev layers publish INTO the output buffer;
// rev layers use a dead buffer.
__global__ void __launch_bounds__(SCAN_THREADS,1)
scan_kernel(const fp16_t* __restrict__ Xi,             // [T*B][3072] fp16
            const unsigned short* __restrict__ WhhT,   // [2560][512] bf16
            const float* __restrict__ bias_l,
            const int* __restrict__ lens,
            unsigned short* __restrict__ Hseq,         // [T][64][512] bf16, 0xFF-sentinel
            unsigned short* __restrict__ xdst,         // bf16 (T,B,H); rev layers only
            float* __restrict__ dout,                  // fp32 (B,T,H); last layer only
            int rev)
{
  __shared__ __align__(16) unsigned short Al[16*HSTR];
  __shared__ float gl[64*GLP];
  __shared__ float bl[80];
  __shared__ int ll[16];

  const int tid = threadIdx.x;
  const int bt  = blockIdx.x & (BT_GROUPS-1);
  const int g   = blockIdx.x >> 2;                     // 0..31
  const int lane = tid & 63, wv = tid >> 6;
  const int frow = lane & 15, quad = lane >> 4;

  for(int i=tid;i<80;i+=SCAN_THREADS) bl[i] = bias_l[(i>>4)*HID + g*16 + (i&15)];
  if(tid<16) ll[tid] = lens[bt*16+tid];
  __syncthreads();

  // register-resident W_hh fragments: 5 gate tiles x 4 ksteps (kstep = wv + 4j)
  bf16x8 Bf[5][4];
  #pragma unroll
  for(int q=0;q<5;q++)
    #pragma unroll
    for(int j=0;j<4;j++)
      Bf[q][j] = *(const bf16x8*)(WhhT + (size_t)(q*HID + g*16 + frow)*HID + (wv + j*4)*32 + quad*8);

  // combine constants: each thread owns one (row, col)
  const int cr = tid >> 4;           // 0..15
  const int jj = tid & 15;           // 0..15
  const int brow_g = bt*16 + cr;
  const int hcol   = g*16 + jj;
  const int L_r = ll[cr];
  float cst=0.f, hs=0.f;
  unsigned short hbf=0; int tprev=0;

  // poll addresses are loop-invariant except for the slot offset
  const size_t pofs[4] = {
    (size_t)((tid      )>>6)*HID + (size_t)((tid      )&63)*8,
    (size_t)((tid+256  )>>6)*HID + (size_t)((tid+256  )&63)*8,
    (size_t)((tid+512  )>>6)*HID + (size_t)((tid+512  )&63)*8,
    (size_t)((tid+768  )>>6)*HID + (size_t)((tid+768  )&63)*8 };

  for(int s=0; s<T_STEPS; s++){
    // ---- phase 1 (rev only): outputs for previous step (fire-and-forget) ----
    if(rev && s>0){
      if(dout) dout[((size_t)brow_g*T_STEPS + tprev)*HID + hcol] = hs;
      else     xdst[((size_t)tprev*BATCH + brow_g)*HID + hcol] = hbf;
    }

    // ---- phase 2: xi prefetch (overlaps poll latency) + poll h(s-1) ----
    bool valid = s < L_r;
    int tcur = rev ? (valid ? (L_r-1-s) : s) : s;
    const fp16_t* xr = Xi + ((size_t)tcur*BATCH + brow_g)*GATES + hcol;
    fp16_t x0v=xr[0], x1v=xr[512], x2v=xr[1024], x3v=xr[1536], x4v=xr[2048], x5v=xr[2560];

    u32x4 hv[4];
    if(s==0){
      #pragma unroll
      for(int i=0;i<4;i++) hv[i] = (u32x4){0u,0u,0u,0u};
    } else {
      const unsigned short* hb = Hseq + (size_t)(s-1)*BATCH*HID + (size_t)bt*16*HID;
      int it = 0;
      while(1){
        #pragma unroll
        for(int i=0;i<4;i++){
          const unsigned short* p = hb + pofs[i];
          asm volatile("global_load_dwordx4 %0, %1, off sc0 sc1" : "=v"(hv[i]) : "v"(p) : "memory");
        }
        // RULE-18 FENCE: tie hv to the waitcnt so the sentinel compares
        // below CANNOT be scheduled before the loads complete.
        asm volatile("s_waitcnt vmcnt(0)"
                     : "+v"(hv[0]), "+v"(hv[1]), "+v"(hv[2]), "+v"(hv[3])
                     :: "memory");
        __builtin_amdgcn_sched_barrier(0);
        unsigned int bad = 0u;
        #pragma unroll
        for(int i=0;i<4;i++){
          bad |= (unsigned)(hv[i][0] == 0xFFFFFFFFu);
          bad |= (unsigned)(hv[i][1] == 0xFFFFFFFFu);
          bad |= (unsigned)(hv[i][2] == 0xFFFFFFFFu);
          bad |= (unsigned)(hv[i][3] == 0xFFFFFFFFu);
        }
        if(!bad) break;
        if(++it > POLL_VALVE) break;        // fail fast (NaN), never hang
        __builtin_amdgcn_s_sleep(1);        // ~64 cy backoff
      }
    }
    #pragma unroll
    for(int i=0;i<4;i++){
      int idx = tid + i*256;
      *(u32x4*)(Al + (idx>>6)*HSTR + (idx&63)*8) = hv[i];
    }
    __syncthreads();  // b2: h staged

    // ---- phase 3: MFMAs (K split mod 4 across waves) + gate partials to LDS ----
    f32x4 acc[5];
    #pragma unroll
    for(int q=0;q<5;q++) acc[q] = (f32x4){0.f,0.f,0.f,0.f};
    #pragma unroll
    for(int j=0;j<4;j++){
      bf16x8 a = *(const bf16x8*)((const bf16_t*)Al + (size_t)frow*HSTR + (wv + j*4)*32 + quad*8);
      #pragma unroll
      for(int q=0;q<5;q++)
        acc[q] = __builtin_amdgcn_mfma_f32_16x16x32_bf16(a, Bf[q][j], acc[q],0,0,0);
    }
    #pragma unroll
    for(int q=0;q<5;q++)
      #pragma unroll
      for(int r4=0;r4<4;r4++)
        gl[(wv*16 + quad*4 + r4)*GLP + q*16 + frow] = acc[q][r4];   // C: col=lane&15, row=quad*4+reg
    __syncthreads();  // b3

    // ---- phase 4: combine + direct publish of h(s) from registers ----
    {
      float ga[5];
      #pragma unroll
      for(int q=0;q<5;q++){
        float sum = bl[q*16+jj];
        #pragma unroll
        for(int w=0;w<4;w++) sum += gl[(w*16+cr)*GLP + q*16 + jj];
        ga[q] = sum;
      }
      ga[0] += (float)x0v; ga[1] += (float)x1v; ga[2] += (float)x2v;
      ga[3] += (float)x3v; ga[4] += (float)x4v;
      float m = valid ? 1.f : 0.f;
      float gi=sigm(ga[0]), gf=sigm(ga[1]), gcv=tanh_f(ga[2]), go=sigm(ga[3]), grv=sigm(ga[4]);
      cst = (gf*cst + gi*gcv) * m;
      hs  = (grv*(go*tanh_f(cst)) + (1.f-grv)*(float)x5v) * m;
      hbf = f2bf(hs);
      tprev = tcur;

      // pair-pack neighboring cols so every store is a whole (atomic) dword
      int up = __shfl_down((int)(unsigned int)hbf, 1);
      if((jj&1)==0){
        unsigned int packed = (unsigned int)hbf | (((unsigned int)up & 0xFFFFu) << 16);
        unsigned int* dst = (unsigned int*)(Hseq + (size_t)s*BATCH*HID + (size_t)brow_g*HID + hcol);
        asm volatile("global_store_dword %0, %1, off sc0 sc1" :: "v"(dst), "v"(packed) : "memory");
      }
    }
    // no trailing barrier: next-iter Al writes fenced from this iter's phase-3
    // reads by b3; next-iter gl writes fenced from phase-4 reads by next b2.
  }

  // epilogue (rev only): outputs for step T-1
  if(rev){
    if(dout) dout[((size_t)brow_g*T_STEPS + tprev)*HID + hcol] = hs;
    else     xdst[((size_t)tprev*BATCH + brow_g)*HID + hcol] = hbf;
  }
}

extern "C" void kernel_launch(void* const* d_in, const int* in_sizes, int n_in,
                              void* d_out, int out_size, void* d_ws, size_t ws_size,
                              hipStream_t stream){
  const float* inp    = (const float*)d_in[0];
  const float* weight = (const float*)d_in[1];
  const float* bias   = (const float*)d_in[2];
  const int*   lens   = (const int*)d_in[3];
  float* dout = (float*)d_out;

  char* ws = (char*)d_ws;
  size_t off = 0;
  const size_t WTL = (size_t)(3072+2560)*512;   // per-layer transposed bf16 elements
  unsigned short* WT = (unsigned short*)(ws+off); off += (size_t)NLAYERS*WTL*2;        // 23.1 MB
  unsigned short* x0 = (unsigned short*)(ws+off); off += (size_t)T_STEPS*BATCH*HID*2;  // 16.8 MB
  unsigned short* xA = (unsigned short*)(ws+off); off += (size_t)T_STEPS*BATCH*HID*2;  // 16.8 MB
  fp16_t* Xi = (fp16_t*)(ws+off); off += (size_t)T_STEPS*BATCH*GATES*2;                // 100.7 MB
  // total 157.3 MB -- no growth vs the proven layout (Hseq aliases x0/xA)

  const size_t HSEQ_BYTES = (size_t)T_STEPS*BATCH*HID*2;                               // 16.8 MB

  const size_t WS_L = (size_t)512*3072 + (size_t)512*2560; // per-layer fp32 weight elements
  for(int l=0;l<NLAYERS;l++){
    const float* wih = weight + l*WS_L;
    const float* whh = wih + (size_t)512*3072;
    unsigned short* wihT = WT + l*WTL;
    unsigned short* whhT = wihT + (size_t)3072*512;
    transpose_cast_kernel<<<dim3(3072/32,512/32),256,0,stream>>>(wih, wihT, 512, 3072);
    transpose_cast_kernel<<<dim3(2560/32,512/32),256,0,stream>>>(whh, whhT, 512, 2560);
  }
  prep_x0_kernel<<<8192,256,0,stream>>>(inp, lens, x0);

  // layer plan (Hseq aliases only dead or output buffers):
  //  l=0: gemm reads x0 -> Hseq = output = xA          (non-rev: publish IS output)
  //  l=1: gemm reads xA -> Hseq = xA (dead), out = x0  (rev)
  //  l=2: gemm reads x0 -> Hseq = output = xA          (non-rev)
  //  l=3: gemm reads xA -> Hseq = x0 (dead), out = dout (rev)
  const unsigned short* gemm_in[4] = {x0, xA, x0, xA};
  unsigned short*       hseq_l[4]  = {xA, xA, xA, x0};
  unsigned short*       xdst_l[4]  = {nullptr, x0, nullptr, nullptr};

  for(int l=0;l<NLAYERS;l++){
    xi_gemm_kernel<<<dim3(128,24),256,0,stream>>>(gemm_in[l], WT + l*WTL, Xi);
    hipMemsetAsync(hseq_l[l], 0xFF, HSEQ_BYTES, stream);  // sentinel fill (after gemm consumed it)
    scan_kernel<<<BT_GROUPS*GBLK, SCAN_THREADS, 0, stream>>>(
        Xi, WT + l*WTL + (size_t)3072*512,
        bias + (size_t)l*2560, lens, hseq_l[l],
        xdst_l[l], (l==3) ? dout : nullptr, l&1);
  }
}

// Round 11
// 2889.992 us; speedup vs baseline: 1.2688x; 1.0068x over previous
//
#include <hip/hip_runtime.h>
#include <hip/hip_bf16.h>
#include <stdint.h>

#define T_STEPS 256
#define BATCH 64
#define HID 512
#define GATES 3072
#define NLAYERS 4
#define BT_GROUPS 4
#define GBLK 32            // blocks per bt-group (each owns 16 h-cols)
#define SCAN_THREADS 256
#define HSTR 520           // h-tile LDS k-stride (elems); 1040 B, 16B-aligned rows
#define GLP 84             // gl float stride (80 + pad)
#define POLL_VALVE 4096    // bounded spin: fails fast (NaN), never hangs

// fused setup kernel block ranges
#define TR_PER_LAYER (1536 + 1280)          // Wih (96x16) + Whh (80x16)
#define SETUP_TR_BLOCKS (NLAYERS*TR_PER_LAYER)   // 11264
#define SETUP_PREP_BLOCKS 8192
#define SETUP_POISON_BLOCKS 4096
#define SETUP_BLOCKS (SETUP_TR_BLOCKS + SETUP_PREP_BLOCKS + SETUP_POISON_BLOCKS)

typedef __bf16 bf16_t;
typedef _Float16 fp16_t;
typedef __attribute__((ext_vector_type(8))) __bf16 bf16x8;
typedef __attribute__((ext_vector_type(4))) float f32x4;
typedef __attribute__((ext_vector_type(4))) unsigned int u32x4;

__device__ __forceinline__ float sigm(float x){ return 1.0f/(1.0f + __expf(-x)); }
__device__ __forceinline__ float tanh_f(float x){ return 2.0f/(1.0f + __expf(-2.0f*x)) - 1.0f; }
__device__ __forceinline__ unsigned short f2bf(float x){ __bf16 b=(__bf16)x; return __builtin_bit_cast(unsigned short, b); }

// async global->LDS, 16B per lane; LDS dest is wave-uniform base + lane*16.
__device__ __forceinline__ void gl_lds16(const unsigned short* g, unsigned short* l){
  __builtin_amdgcn_global_load_lds(
      (const __attribute__((address_space(1))) void*)(uintptr_t)g,
      (__attribute__((address_space(3))) void*)(uintptr_t)l,
      16, 0, 0);
}

// ---- fused setup: 8 weight transposes + input prep + layer-0 Hseq poison ----
// One launch replaces 9 serial dispatches (8 transpose + prep) + 1 memset.
// Branches are block-uniform; all three jobs are independent.
__global__ void setup_kernel(const float* __restrict__ weight,
                             const float* __restrict__ inp,
                             const int* __restrict__ lens,
                             unsigned short* __restrict__ WT,
                             unsigned short* __restrict__ x0,
                             unsigned short* __restrict__ xA){
  const size_t WTL  = (size_t)(3072+2560)*512;
  const size_t WS_L = (size_t)512*3072 + (size_t)512*2560;
  int bid = blockIdx.x;
  if(bid < SETUP_TR_BLOCKS){
    // transpose+cast fp32 [512][C] -> bf16 [C][512]
    int l = bid / TR_PER_LAYER, r = bid % TR_PER_LAYER;
    const float* src; unsigned short* dst; int C, bx, by;
    const float* wih = weight + (size_t)l*WS_L;
    if(r < 1536){ src = wih;                     dst = WT + l*WTL;                       C = 3072; bx = r % 96; by = r / 96; }
    else        { int r2 = r - 1536; src = wih + (size_t)512*3072;
                  dst = WT + l*WTL + (size_t)3072*512;                                  C = 2560; bx = r2 % 80; by = r2 / 80; }
    __shared__ float tile[32][33];
    int tx = threadIdx.x & 31, ty = threadIdx.x >> 5;
    int c0 = bx*32, r0 = by*32;
    #pragma unroll
    for(int i=0;i<4;i++){ int rr = r0 + ty + i*8; tile[ty+i*8][tx] = src[(size_t)rr*C + c0 + tx]; }
    __syncthreads();
    #pragma unroll
    for(int i=0;i<4;i++){ int c = c0 + ty + i*8; dst[(size_t)c*512 + r0 + tx] = f2bf(tile[tx][ty+i*8]); }
  } else if(bid < SETUP_TR_BLOCKS + SETUP_PREP_BLOCKS){
    // inputs (B,T,D) fp32 -> masked bf16 (T,B,D)
    int idx = (bid - SETUP_TR_BLOCKS)*blockDim.x + threadIdx.x;
    int e = idx*4;
    int d = e & (HID-1);
    int tb = e >> 9;
    int b = tb & (BATCH-1);
    int t = tb >> 6;
    const float4 v = *(const float4*)(inp + ((size_t)b*T_STEPS + t)*HID + d);
    float m = (t < lens[b]) ? 1.f : 0.f;
    ushort4 u; u.x=f2bf(v.x*m); u.y=f2bf(v.y*m); u.z=f2bf(v.z*m); u.w=f2bf(v.w*m);
    *(ushort4*)(x0 + ((size_t)t*BATCH + b)*HID + d) = u;
  } else {
    // poison xA with 0xFF sentinel for layer-0's Hseq (gemm 0 never touches xA)
    int k = (bid - SETUP_TR_BLOCKS - SETUP_PREP_BLOCKS)*blockDim.x + threadIdx.x;
    *(u32x4*)(xA + (size_t)k*8) =
        (u32x4){0xFFFFFFFFu,0xFFFFFFFFu,0xFFFFFFFFu,0xFFFFFFFFu};
  }
}

// ---- xi GEMM: C[m][n] = A[m][:] @ BT[n][:],  M=16384, N=3072, K=512, out fp16 ----
// (r10-proven: global_load_lds width=16 staging, linear [128][64] LDS; ~60us)
__global__ void __launch_bounds__(256,2)
xi_gemm_kernel(const unsigned short* __restrict__ A,   // [16384][512] bf16
               const unsigned short* __restrict__ BT,  // [3072][512] bf16 (WihT)
               fp16_t* __restrict__ C)                  // [16384][3072] fp16
{
  __shared__ __align__(16) unsigned short As[128*64];
  __shared__ __align__(16) unsigned short Bs[128*64];
  const int tid = threadIdx.x, lane = tid & 63, wv = tid >> 6;
  const int frow = lane & 15, quad = lane >> 4;
  const int m0 = blockIdx.x*128, n0 = blockIdx.y*128;
  const int mh = (wv>>1)*64, nh = (wv&1)*64;
  f32x4 acc[4][4];
  #pragma unroll
  for(int mt=0;mt<4;mt++)
    #pragma unroll
    for(int nt=0;nt<4;nt++) acc[mt][nt] = (f32x4){0.f,0.f,0.f,0.f};

  const unsigned short* gA0 = A  + (size_t)(m0 + wv*8 + (lane>>3))*512 + (lane&7)*8;
  const unsigned short* gB0 = BT + (size_t)(n0 + wv*8 + (lane>>3))*512 + (lane&7)*8;
  unsigned short* lA0 = As + (wv*8)*64;   // wave-uniform LDS bases
  unsigned short* lB0 = Bs + (wv*8)*64;

  for(int kc=0;kc<512;kc+=64){
    #pragma unroll
    for(int i=0;i<4;i++){
      gl_lds16(gA0 + kc + (size_t)i*32*512, lA0 + i*32*64);
      gl_lds16(gB0 + kc + (size_t)i*32*512, lB0 + i*32*64);
    }
    asm volatile("s_waitcnt vmcnt(0)" ::: "memory");
    __syncthreads();
    #pragma unroll
    for(int ks=0;ks<2;ks++){
      bf16x8 av[4], bv[4];
      #pragma unroll
      for(int mt=0;mt<4;mt++) av[mt] = *(const bf16x8*)(As + (mh+mt*16+frow)*64 + ks*32 + quad*8);
      #pragma unroll
      for(int nt=0;nt<4;nt++) bv[nt] = *(const bf16x8*)(Bs + (nh+nt*16+frow)*64 + ks*32 + quad*8);
      #pragma unroll
      for(int mt=0;mt<4;mt++)
        #pragma unroll
        for(int nt=0;nt<4;nt++)
          acc[mt][nt] = __builtin_amdgcn_mfma_f32_16x16x32_bf16(av[mt], bv[nt], acc[mt][nt],0,0,0);
    }
    __syncthreads();
  }
  #pragma unroll
  for(int mt=0;mt<4;mt++)
    #pragma unroll
    for(int nt=0;nt<4;nt++)
      #pragma unroll
      for(int r4=0;r4<4;r4++)
        C[(size_t)(m0+mh+mt*16+quad*4+r4)*GATES + n0+nh+nt*16+frow] = (fp16_t)acc[mt][nt][r4];
}

// ---- fused per-layer scan -- BYTE-IDENTICAL to the proven round-4 kernel ----
// (642 us/dispatch verified; r5-r9 exchange experiments all lost to it.)
// SELF-FLAGGING exchange: Hseq[s][64][512] bf16, 0xFF-prefilled (bf16 NaN
// pattern, unproducible by finite math; masked rows give exact 0.0). A dword
// == 0xFFFFFFFF means "not yet written"; dword stores are atomic.
// RULE-18 FENCE: waitcnt asm takes hv[0..3] as "+v" + sched_barrier(0).
// BOUNDED SPIN: valve 4096 + s_sleep backoff (fail fast, never hang).
// ZERO-GROWTH ALIASING: non-rev layers publish INTO the output buffer;
// rev layers use a dead buffer.
__global__ void __launch_bounds__(SCAN_THREADS,1)
scan_kernel(const fp16_t* __restrict__ Xi,             // [T*B][3072] fp16
            const unsigned short* __restrict__ WhhT,   // [2560][512] bf16
            const float* __restrict__ bias_l,
            const int* __restrict__ lens,
            unsigned short* __restrict__ Hseq,         // [T][64][512] bf16, 0xFF-sentinel
            unsigned short* __restrict__ xdst,         // bf16 (T,B,H); rev layers only
            float* __restrict__ dout,                  // fp32 (B,T,H); last layer only
            int rev)
{
  __shared__ __align__(16) unsigned short Al[16*HSTR];
  __shared__ float gl[64*GLP];
  __shared__ float bl[80];
  __shared__ int ll[16];

  const int tid = threadIdx.x;
  const int bt  = blockIdx.x & (BT_GROUPS-1);
  const int g   = blockIdx.x >> 2;                     // 0..31
  const int lane = tid & 63, wv = tid >> 6;
  const int frow = lane & 15, quad = lane >> 4;

  for(int i=tid;i<80;i+=SCAN_THREADS) bl[i] = bias_l[(i>>4)*HID + g*16 + (i&15)];
  if(tid<16) ll[tid] = lens[bt*16+tid];
  __syncthreads();

  // register-resident W_hh fragments: 5 gate tiles x 4 ksteps (kstep = wv + 4j)
  bf16x8 Bf[5][4];
  #pragma unroll
  for(int q=0;q<5;q++)
    #pragma unroll
    for(int j=0;j<4;j++)
      Bf[q][j] = *(const bf16x8*)(WhhT + (size_t)(q*HID + g*16 + frow)*HID + (wv + j*4)*32 + quad*8);

  // combine constants: each thread owns one (row, col)
  const int cr = tid >> 4;           // 0..15
  const int jj = tid & 15;           // 0..15
  const int brow_g = bt*16 + cr;
  const int hcol   = g*16 + jj;
  const int L_r = ll[cr];
  float cst=0.f, hs=0.f;
  unsigned short hbf=0; int tprev=0;

  // poll addresses are loop-invariant except for the slot offset
  const size_t pofs[4] = {
    (size_t)((tid      )>>6)*HID + (size_t)((tid      )&63)*8,
    (size_t)((tid+256  )>>6)*HID + (size_t)((tid+256  )&63)*8,
    (size_t)((tid+512  )>>6)*HID + (size_t)((tid+512  )&63)*8,
    (size_t)((tid+768  )>>6)*HID + (size_t)((tid+768  )&63)*8 };

  for(int s=0; s<T_STEPS; s++){
    // ---- phase 1 (rev only): outputs for previous step (fire-and-forget) ----
    if(rev && s>0){
      if(dout) dout[((size_t)brow_g*T_STEPS + tprev)*HID + hcol] = hs;
      else     xdst[((size_t)tprev*BATCH + brow_g)*HID + hcol] = hbf;
    }

    // ---- phase 2: xi prefetch (overlaps poll latency) + poll h(s-1) ----
    bool valid = s < L_r;
    int tcur = rev ? (valid ? (L_r-1-s) : s) : s;
    const fp16_t* xr = Xi + ((size_t)tcur*BATCH + brow_g)*GATES + hcol;
    fp16_t x0v=xr[0], x1v=xr[512], x2v=xr[1024], x3v=xr[1536], x4v=xr[2048], x5v=xr[2560];

    u32x4 hv[4];
    if(s==0){
      #pragma unroll
      for(int i=0;i<4;i++) hv[i] = (u32x4){0u,0u,0u,0u};
    } else {
      const unsigned short* hb = Hseq + (size_t)(s-1)*BATCH*HID + (size_t)bt*16*HID;
      int it = 0;
      while(1){
        #pragma unroll
        for(int i=0;i<4;i++){
          const unsigned short* p = hb + pofs[i];
          asm volatile("global_load_dwordx4 %0, %1, off sc0 sc1" : "=v"(hv[i]) : "v"(p) : "memory");
        }
        // RULE-18 FENCE: tie hv to the waitcnt so the sentinel compares
        // below CANNOT be scheduled before the loads complete.
        asm volatile("s_waitcnt vmcnt(0)"
                     : "+v"(hv[0]), "+v"(hv[1]), "+v"(hv[2]), "+v"(hv[3])
                     :: "memory");
        __builtin_amdgcn_sched_barrier(0);
        unsigned int bad = 0u;
        #pragma unroll
        for(int i=0;i<4;i++){
          bad |= (unsigned)(hv[i][0] == 0xFFFFFFFFu);
          bad |= (unsigned)(hv[i][1] == 0xFFFFFFFFu);
          bad |= (unsigned)(hv[i][2] == 0xFFFFFFFFu);
          bad |= (unsigned)(hv[i][3] == 0xFFFFFFFFu);
        }
        if(!bad) break;
        if(++it > POLL_VALVE) break;        // fail fast (NaN), never hang
        __builtin_amdgcn_s_sleep(1);        // ~64 cy backoff
      }
    }
    #pragma unroll
    for(int i=0;i<4;i++){
      int idx = tid + i*256;
      *(u32x4*)(Al + (idx>>6)*HSTR + (idx&63)*8) = hv[i];
    }
    __syncthreads();  // b2: h staged

    // ---- phase 3: MFMAs (K split mod 4 across waves) + gate partials to LDS ----
    f32x4 acc[5];
    #pragma unroll
    for(int q=0;q<5;q++) acc[q] = (f32x4){0.f,0.f,0.f,0.f};
    #pragma unroll
    for(int j=0;j<4;j++){
      bf16x8 a = *(const bf16x8*)((const bf16_t*)Al + (size_t)frow*HSTR + (wv + j*4)*32 + quad*8);
      #pragma unroll
      for(int q=0;q<5;q++)
        acc[q] = __builtin_amdgcn_mfma_f32_16x16x32_bf16(a, Bf[q][j], acc[q],0,0,0);
    }
    #pragma unroll
    for(int q=0;q<5;q++)
      #pragma unroll
      for(int r4=0;r4<4;r4++)
        gl[(wv*16 + quad*4 + r4)*GLP + q*16 + frow] = acc[q][r4];   // C: col=lane&15, row=quad*4+reg
    __syncthreads();  // b3

    // ---- phase 4: combine + direct publish of h(s) from registers ----
    {
      float ga[5];
      #pragma unroll
      for(int q=0;q<5;q++){
        float sum = bl[q*16+jj];
        #pragma unroll
        for(int w=0;w<4;w++) sum += gl[(w*16+cr)*GLP + q*16 + jj];
        ga[q] = sum;
      }
      ga[0] += (float)x0v; ga[1] += (float)x1v; ga[2] += (float)x2v;
      ga[3] += (float)x3v; ga[4] += (float)x4v;
      float m = valid ? 1.f : 0.f;
      float gi=sigm(ga[0]), gf=sigm(ga[1]), gcv=tanh_f(ga[2]), go=sigm(ga[3]), grv=sigm(ga[4]);
      cst = (gf*cst + gi*gcv) * m;
      hs  = (grv*(go*tanh_f(cst)) + (1.f-grv)*(float)x5v) * m;
      hbf = f2bf(hs);
      tprev = tcur;

      // pair-pack neighboring cols so every store is a whole (atomic) dword
      int up = __shfl_down((int)(unsigned int)hbf, 1);
      if((jj&1)==0){
        unsigned int packed = (unsigned int)hbf | (((unsigned int)up & 0xFFFFu) << 16);
        unsigned int* dst = (unsigned int*)(Hseq + (size_t)s*BATCH*HID + (size_t)brow_g*HID + hcol);
        asm volatile("global_store_dword %0, %1, off sc0 sc1" :: "v"(dst), "v"(packed) : "memory");
      }
    }
    // no trailing barrier: next-iter Al writes fenced from this iter's phase-3
    // reads by b3; next-iter gl writes fenced from phase-4 reads by next b2.
  }

  // epilogue (rev only): outputs for step T-1
  if(rev){
    if(dout) dout[((size_t)brow_g*T_STEPS + tprev)*HID + hcol] = hs;
    else     xdst[((size_t)tprev*BATCH + brow_g)*HID + hcol] = hbf;
  }
}

extern "C" void kernel_launch(void* const* d_in, const int* in_sizes, int n_in,
                              void* d_out, int out_size, void* d_ws, size_t ws_size,
                              hipStream_t stream){
  const float* inp    = (const float*)d_in[0];
  const float* weight = (const float*)d_in[1];
  const float* bias   = (const float*)d_in[2];
  const int*   lens   = (const int*)d_in[3];
  float* dout = (float*)d_out;

  char* ws = (char*)d_ws;
  size_t off = 0;
  const size_t WTL = (size_t)(3072+2560)*512;   // per-layer transposed bf16 elements
  unsigned short* WT = (unsigned short*)(ws+off); off += (size_t)NLAYERS*WTL*2;        // 23.1 MB
  unsigned short* x0 = (unsigned short*)(ws+off); off += (size_t)T_STEPS*BATCH*HID*2;  // 16.8 MB
  unsigned short* xA = (unsigned short*)(ws+off); off += (size_t)T_STEPS*BATCH*HID*2;  // 16.8 MB
  fp16_t* Xi = (fp16_t*)(ws+off); off += (size_t)T_STEPS*BATCH*GATES*2;                // 100.7 MB
  // total 157.3 MB -- no growth vs the proven layout (Hseq aliases x0/xA)

  const size_t HSEQ_BYTES = (size_t)T_STEPS*BATCH*HID*2;                               // 16.8 MB

  // fused setup: 8 transposes + prep_x0 + layer-0 sentinel poison, one launch
  setup_kernel<<<SETUP_BLOCKS,256,0,stream>>>(weight, inp, lens, WT, x0, xA);

  // layer plan (Hseq aliases only dead or output buffers):
  //  l=0: gemm reads x0 -> Hseq = output = xA          (non-rev: publish IS output)
  //  l=1: gemm reads xA -> Hseq = xA (dead), out = x0  (rev)
  //  l=2: gemm reads x0 -> Hseq = output = xA          (non-rev)
  //  l=3: gemm reads xA -> Hseq = x0 (dead), out = dout (rev)
  const unsigned short* gemm_in[4] = {x0, xA, x0, xA};
  unsigned short*       hseq_l[4]  = {xA, xA, xA, x0};
  unsigned short*       xdst_l[4]  = {nullptr, x0, nullptr, nullptr};

  for(int l=0;l<NLAYERS;l++){
    xi_gemm_kernel<<<dim3(128,24),256,0,stream>>>(gemm_in[l], WT + l*WTL, Xi);
    if(l > 0)  // layer 0's poison was folded into setup_kernel
      hipMemsetAsync(hseq_l[l], 0xFF, HSEQ_BYTES, stream);
    scan_kernel<<<BT_GROUPS*GBLK, SCAN_THREADS, 0, stream>>>(
        Xi, WT + l*WTL + (size_t)3072*512,
        bias + (size_t)l*2560, lens, hseq_l[l],
        xdst_l[l], (l==3) ? dout : nullptr, l&1);
  }
}